// Round 5
// baseline (61.669 us; speedup 1.0000x reference)
//
#include <hip/hip_runtime.h>

// LIF neuron forward scan: x [B,N,T] f32, T=256 contiguous (last axis).
// Per sequence: u = u*TAU + x_t; s = (u >= VTH); u = s ? V_R : u; emit s.
// TAU=0.125 (power of two -> u*TAU exact -> recurrence bit-matches numpy ref).

constexpr int   T   = 256;
constexpr int   TV  = T / 4;     // 64 float4 per sequence
constexpr float TAU = 0.125f;
constexpr float VTH = 1.0f;

__global__ __launch_bounds__(256)
void lif_fwd(const float4* __restrict__ x, float4* __restrict__ out, int nseq) {
    int seq = blockIdx.x * blockDim.x + threadIdx.x;
    if (seq >= nseq) return;

    const float4* xp = x   + (size_t)seq * TV;
    float4*       op = out + (size_t)seq * TV;

    float u = 0.0f;
#pragma unroll 8
    for (int c = 0; c < TV; ++c) {
        float4 v = xp[c];   // independent of recurrence -> compiler can hoist/pipeline
        float4 s;
        u = u * TAU + v.x; { bool b = (u >= VTH); s.x = b ? 1.0f : 0.0f; u = b ? 0.0f : u; }
        u = u * TAU + v.y; { bool b = (u >= VTH); s.y = b ? 1.0f : 0.0f; u = b ? 0.0f : u; }
        u = u * TAU + v.z; { bool b = (u >= VTH); s.z = b ? 1.0f : 0.0f; u = b ? 0.0f : u; }
        u = u * TAU + v.w; { bool b = (u >= VTH); s.w = b ? 1.0f : 0.0f; u = b ? 0.0f : u; }
        op[c] = s;
    }
}

extern "C" void kernel_launch(void* const* d_in, const int* in_sizes, int n_in,
                              void* d_out, int out_size, void* d_ws, size_t ws_size,
                              hipStream_t stream) {
    const float* x = (const float*)d_in[0];
    float* out = (float*)d_out;

    int nseq = in_sizes[0] / T;          // 32*4096 = 131072 sequences
    int block = 256;
    int grid  = (nseq + block - 1) / block;

    lif_fwd<<<grid, block, 0, stream>>>(
        (const float4*)x, (float4*)out, nseq);
}